// Round 9
// baseline (986.585 us; speedup 1.0000x reference)
//
#include <hip/hip_runtime.h>
#include <math.h>

#define NN 100000
#define NE 3200000
#define NG 512
#define D 16
#define SLOPE 0.01f
#define BT 256
#define CAP 80   // padded-CSR slots per node; CAP%16==0; col src = rp/CAP

__device__ __forceinline__ float leakyf(float x){ return x >= 0.0f ? x : SLOPE*x; }
__device__ __forceinline__ float dleakyf(float x){ return x >= 0.0f ? 1.0f : SLOPE; }

__device__ __forceinline__ float red16(float v){
  v += __shfl_xor(v, 8, 16);
  v += __shfl_xor(v, 4, 16);
  v += __shfl_xor(v, 2, 16);
  v += __shfl_xor(v, 1, 16);
  return v;
}

// fused: pos repack + (compact-only) offsets written later by k_offsets
__global__ void k_pos4(const float* __restrict__ pos, float4* __restrict__ pos4){
  int n = blockIdx.x*blockDim.x + threadIdx.x;
  if (n >= NN) return;
  pos4[n] = make_float4(pos[3*n+0], pos[3*n+1], pos[3*n+2], 0.0f);
}

// ---- CSR build, compact path (count + scan + place) ----------------------
__global__ void k_count(const int* __restrict__ ei, int* __restrict__ cnt_row,
                        int* __restrict__ cnt_col){
  int t = blockIdx.x*blockDim.x + threadIdx.x;
  if (t >= NE/4) return;
  int4 r4 = ((const int4*)ei)[t];
  int4 c4 = ((const int4*)(ei + NE))[t];
  atomicAdd(&cnt_row[r4.x], 1); atomicAdd(&cnt_row[r4.y], 1);
  atomicAdd(&cnt_row[r4.z], 1); atomicAdd(&cnt_row[r4.w], 1);
  atomicAdd(&cnt_col[c4.x], 1); atomicAdd(&cnt_col[c4.y], 1);
  atomicAdd(&cnt_col[c4.z], 1); atomicAdd(&cnt_col[c4.w], 1);
}

__global__ void k_blocksum(const int* __restrict__ cnt_row, const int* __restrict__ cnt_col,
                           int* __restrict__ bsum){
  const int* src = blockIdx.y ? cnt_col : cnt_row;
  __shared__ int s[BT];
  int i = blockIdx.x*BT + threadIdx.x;
  s[threadIdx.x] = (i < NN) ? src[i] : 0;
  __syncthreads();
  for (int off = BT/2; off > 0; off >>= 1){
    if (threadIdx.x < off) s[threadIdx.x] += s[threadIdx.x+off];
    __syncthreads();
  }
  if (threadIdx.x == 0) bsum[blockIdx.y*512 + blockIdx.x] = s[0];
}

__global__ void k_scan_bsum(int* __restrict__ bsum, int nb){
  int* b = bsum + blockIdx.y*512;
  __shared__ int s0[512], s1[512];
  int tid = threadIdx.x;
  int v = (tid < nb) ? b[tid] : 0;
  s0[tid] = v; __syncthreads();
  int rd = 0;
  for (int off = 1; off < 512; off <<= 1){
    int x = rd ? s1[tid] : s0[tid];
    if (tid >= off) x += rd ? s1[tid-off] : s0[tid-off];
    if (rd) s0[tid] = x; else s1[tid] = x;
    __syncthreads();
    rd ^= 1;
  }
  int incl = rd ? s1[tid] : s0[tid];
  if (tid < nb) b[tid] = incl - v;
}

__global__ void k_offsets(const int* __restrict__ cnt_row, const int* __restrict__ cnt_col,
                          const int* __restrict__ bsum,
                          int* __restrict__ off_row, int* __restrict__ off_col,
                          int* __restrict__ cur_row, int* __restrict__ cur_col){
  const int* src  = blockIdx.y ? cnt_col : cnt_row;
  int* offd = blockIdx.y ? off_col : off_row;
  int* curd = blockIdx.y ? cur_col : cur_row;
  __shared__ int s0[BT], s1[BT];
  int tid = threadIdx.x;
  int i = blockIdx.x*BT + tid;
  int v = (i < NN) ? src[i] : 0;
  s0[tid] = v; __syncthreads();
  int rd = 0;
  for (int off = 1; off < BT; off <<= 1){
    int x = rd ? s1[tid] : s0[tid];
    if (tid >= off) x += rd ? s1[tid-off] : s0[tid-off];
    if (rd) s0[tid] = x; else s1[tid] = x;
    __syncthreads();
    rd ^= 1;
  }
  int incl = rd ? s1[tid] : s0[tid];
  if (i < NN){
    int o = bsum[blockIdx.y*512 + blockIdx.x] + incl - v;
    offd[i] = o; curd[i] = o;
  }
}

// compact place: SoA 4B scattered stores, col_src kept
__global__ void k_place(const int* __restrict__ ei, const float4* __restrict__ pos4,
                        int* __restrict__ cur_row, int* __restrict__ cur_col,
                        int* __restrict__ row_dst, float* __restrict__ row_w,
                        int* __restrict__ col_src, int* __restrict__ col_rp,
                        float* __restrict__ col_w){
  int e = blockIdx.x*blockDim.x + threadIdx.x;
  if (e >= NE) return;
  int r = ei[e], c = ei[NE+e];
  float4 pr = pos4[r], pc = pos4[c];
  float dx = pr.x-pc.x, dy = pr.y-pc.y, dz = pr.z-pc.z;
  float w = sqrtf(dx*dx+dy*dy+dz*dz);
  int p = atomicAdd(&cur_row[r], 1);
  int q = atomicAdd(&cur_col[c], 1);
  row_dst[p] = c; row_w[p] = w;
  col_src[q] = r; col_rp[q] = p; col_w[q] = w;
}

// padded place: base = n*CAP analytic; col_src DERIVED (= rp/CAP), not stored.
// 6 scattered ops/edge: 2 atomics + 4 stores.
__global__ void k_place_pad(const int* __restrict__ ei, const float4* __restrict__ pos4,
                            int* __restrict__ cnt_row, int* __restrict__ cnt_col,
                            int* __restrict__ row_dst, float* __restrict__ row_w,
                            int* __restrict__ col_rp, float* __restrict__ col_w){
  int e = blockIdx.x*blockDim.x + threadIdx.x;
  if (e >= NE) return;
  int r = ei[e], c = ei[NE+e];
  float4 pr = pos4[r], pc = pos4[c];
  float dx = pr.x-pc.x, dy = pr.y-pc.y, dz = pr.z-pc.z;
  float w = sqrtf(dx*dx+dy*dy+dz*dz);
  int p = r*CAP + atomicAdd(&cnt_row[r], 1);
  int q = c*CAP + atomicAdd(&cnt_col[c], 1);
  row_dst[p] = c; row_w[p] = w;
  col_rp[q] = p; col_w[q] = w;
}

// zero-fill pad slots [cnt, roundup16(cnt)): w=0 kills contributions,
// rp=0 -> derived src=0 (valid), dst=0 (valid).
__global__ void k_padzero(const int* __restrict__ cnt_row, const int* __restrict__ cnt_col,
                          int* __restrict__ row_dst, float* __restrict__ row_w,
                          int* __restrict__ col_rp, float* __restrict__ col_w){
  int t = blockIdx.x*blockDim.x + threadIdx.x;
  int n = t >> 4, k = t & 15;
  if (n >= NN) return;
  int cr = cnt_row[n], er = (cr + 15) & ~15;
  if (cr + k < er){ row_dst[n*CAP + cr + k] = 0; row_w[n*CAP + cr + k] = 0.f; }
  int cc = cnt_col[n], ec = (cc + 15) & ~15;
  if (cc + k < ec){ col_rp[n*CAP + cc + k] = 0; col_w[n*CAP + cc + k] = 0.f; }
}

// ---- forward ------------------------------------------------------------
__global__ void k_dinv_y1(const float* __restrict__ col_w, const int* __restrict__ off_col,
                          const int* __restrict__ cnt_col,
                          const float* __restrict__ emb, const int* __restrict__ z,
                          const float* __restrict__ W1,
                          float* __restrict__ dinv, float* __restrict__ ys1, int pad16){
  __shared__ float sW[D*D];
  for (int i = threadIdx.x; i < D*D; i += blockDim.x) sW[i] = W1[i];
  __syncthreads();
  int t = blockIdx.x*blockDim.x + threadIdx.x;
  int n = t >> 4, k = t & 15;
  if (n >= NN) return;
  int base = pad16 ? n*CAP : off_col[n];
  int cnt = cnt_col[n];
  float s = 0.f;
  for (int i = k; i < cnt; i += 16) s += col_w[base+i];
  s = red16(s);
  float dv = 1.0f / sqrtf(1.0f + s);
  if (k == 0) dinv[n] = dv;
  float h = emb[z[n]*D + k];
  float acc = 0.f;
  #pragma unroll
  for (int j = 0; j < D; j++) acc += __shfl(h, j, 16)*sW[j*D+k];
  ys1[n*D+k] = dv*acc;
}

// conv1 gather (16-edge blocks; padded: src = rp/CAP) + MLP mid
__global__ void k_conv1_mid(const int* __restrict__ col_si, const float* __restrict__ col_w,
                            const int* __restrict__ off_col, const int* __restrict__ cnt_col,
                            const float* __restrict__ dinv, const float* __restrict__ ys1,
                            const float* __restrict__ b1, const float* __restrict__ Wl1,
                            const float* __restrict__ bl1, const float* __restrict__ W2,
                            float* __restrict__ ys2, unsigned* __restrict__ masks,
                            int pad16){
  __shared__ float sWl1[D*D], sW2[D*D], sb1[D], sbl1[D];
  for (int i = threadIdx.x; i < D*D; i += blockDim.x){ sWl1[i] = Wl1[i]; sW2[i] = W2[i]; }
  if (threadIdx.x < D){ sb1[threadIdx.x] = b1[threadIdx.x]; sbl1[threadIdx.x] = bl1[threadIdx.x]; }
  __syncthreads();
  int t = blockIdx.x*blockDim.x + threadIdx.x;
  int n = t >> 4, k = t & 15;
  if (n >= NN) return;
  int base = pad16 ? n*CAP : off_col[n];
  int cnt = cnt_col[n];
  int cend = (cnt + (pad16 ? 15 : 0)) & ~15;
  float acc = 0.f;
  int i = 0;
  for (; i < cend; i += 16){
    int   se = col_si[base+i+k];          // rp (padded) or src (compact)
    if (pad16) se /= CAP;                 // 1 divide per edge, pre-broadcast
    float we = col_w[base+i+k];
    #pragma unroll
    for (int j = 0; j < 16; j++){
      int   sj = __shfl(se, j, 16);
      float wj = __shfl(we, j, 16);
      acc += wj * ys1[sj*D+k];
    }
  }
  for (; i < cnt; i++){
    int se = col_si[base+i];
    if (pad16) se /= CAP;
    acc += col_w[base+i]*ys1[se*D+k];
  }
  float dv = dinv[n];
  float u1 = dv*(acc + ys1[n*D+k]) + sb1[k];
  float h1 = leakyf(u1);
  float u2 = sbl1[k];
  #pragma unroll
  for (int j = 0; j < D; j++) u2 += __shfl(h1, j, 16)*sWl1[j*D+k];
  float h2 = leakyf(u2);
  float yo = 0.f;
  #pragma unroll
  for (int j = 0; j < D; j++) yo += __shfl(h2, j, 16)*sW2[j*D+k];
  ys2[n*D+k] = dv*yo;
  unsigned mm = ((u1 >= 0.f) ? (1u<<k) : 0u) | ((u2 >= 0.f) ? (1u<<(16+k)) : 0u);
  mm |= (unsigned)__shfl_xor((int)mm, 8, 16);
  mm |= (unsigned)__shfl_xor((int)mm, 4, 16);
  mm |= (unsigned)__shfl_xor((int)mm, 2, 16);
  mm |= (unsigned)__shfl_xor((int)mm, 1, 16);
  if (k == 0) masks[n] = mm;
}

// conv2 gather + head + energy + head backward: ds3, gdiag_s
__global__ void k_conv2_out(const int* __restrict__ col_si, const float* __restrict__ col_w,
                            const int* __restrict__ off_col, const int* __restrict__ cnt_col,
                            const float* __restrict__ dinv, const float* __restrict__ ys2,
                            const int* __restrict__ batch,
                            const float* __restrict__ b2, const float* __restrict__ Wl2,
                            const float* __restrict__ bl2, const float* __restrict__ Wl3,
                            const float* __restrict__ bl3,
                            float* __restrict__ Eout, float* __restrict__ ds3,
                            float* __restrict__ gdiag, int pad16){
  __shared__ float sWl2[D*4], sb2[D], sbl2[4], sWl3[4], sbl3s;
  if (threadIdx.x < D*4) sWl2[threadIdx.x] = Wl2[threadIdx.x];
  if (threadIdx.x < D) sb2[threadIdx.x] = b2[threadIdx.x];
  if (threadIdx.x < 4){ sbl2[threadIdx.x] = bl2[threadIdx.x]; sWl3[threadIdx.x] = Wl3[threadIdx.x]; }
  if (threadIdx.x == 0) sbl3s = bl3[0];
  __syncthreads();
  int t = blockIdx.x*blockDim.x + threadIdx.x;
  int n = t >> 4, k = t & 15;
  if (n >= NN) return;
  int base = pad16 ? n*CAP : off_col[n];
  int cnt = cnt_col[n];
  int cend = (cnt + (pad16 ? 15 : 0)) & ~15;
  float acc = 0.f;
  int i = 0;
  for (; i < cend; i += 16){
    int   se = col_si[base+i+k];
    if (pad16) se /= CAP;
    float we = col_w[base+i+k];
    #pragma unroll
    for (int j = 0; j < 16; j++){
      int   sj = __shfl(se, j, 16);
      float wj = __shfl(we, j, 16);
      acc += wj * ys2[sj*D+k];
    }
  }
  for (; i < cnt; i++){
    int se = col_si[base+i];
    if (pad16) se /= CAP;
    acc += col_w[base+i]*ys2[se*D+k];
  }
  float dv = dinv[n];
  float ysk = ys2[n*D+k];
  float u3 = dv*(acc + ysk) + sb2[k];
  float h3 = leakyf(u3);
  float u40 = sbl2[0], u41 = sbl2[1], u42 = sbl2[2], u43 = sbl2[3];
  #pragma unroll
  for (int j = 0; j < D; j++){
    float hj = __shfl(h3, j, 16);
    u40 += hj*sWl2[j*4+0]; u41 += hj*sWl2[j*4+1];
    u42 += hj*sWl2[j*4+2]; u43 += hj*sWl2[j*4+3];
  }
  float h40 = leakyf(u40), h41 = leakyf(u41), h42 = leakyf(u42), h43 = leakyf(u43);
  float u5 = sbl3s + h40*sWl3[0] + h41*sWl3[1] + h42*sWl3[2] + h43*sWl3[3];
  float h5 = leakyf(u5);
  if (k == 0) atomicAdd(&Eout[batch[n]], h5);
  float du5 = dleakyf(u5);
  float d40 = du5*sWl3[0]*dleakyf(u40);
  float d41 = du5*sWl3[1]*dleakyf(u41);
  float d42 = du5*sWl3[2]*dleakyf(u42);
  float d43 = du5*sWl3[3]*dleakyf(u43);
  float g = d40*sWl2[k*4+0] + d41*sWl2[k*4+1] + d42*sWl2[k*4+2] + d43*sWl2[k*4+3];
  float d3 = g*dleakyf(u3);
  ds3[n*D+k] = dv*d3;
  float gd = red16(d3*ysk);          // gdiag_s = dv * (du3 . y2)
  if (k == 0) gdiag[n] = gd;
}

// ---- backward -----------------------------------------------------------
// FUSED row pass 2 + node mid chain. Pad-slot gn writes are finite garbage,
// only ever multiplied by w=0 downstream.
__global__ void k_bwd2mid(const int* __restrict__ row_dst, const float* __restrict__ row_w,
                          const int* __restrict__ off_row, const int* __restrict__ cnt_row,
                          const float* __restrict__ dinv, const float* __restrict__ ys1,
                          const float* __restrict__ ys2, const float* __restrict__ ds3,
                          const unsigned* __restrict__ masks,
                          const float* __restrict__ W2, const float* __restrict__ Wl1,
                          float* __restrict__ gn_row, float* __restrict__ ds1,
                          float* __restrict__ gdiag, int pad16){
  __shared__ float sW2[D*D], sWl1[D*D];
  for (int i = threadIdx.x; i < D*D; i += blockDim.x){ sW2[i] = W2[i]; sWl1[i] = Wl1[i]; }
  __syncthreads();
  int t = blockIdx.x*blockDim.x + threadIdx.x;
  int n = t >> 4, k = t & 15;
  if (n >= NN) return;
  int base = pad16 ? n*CAP : off_row[n];
  int cnt = cnt_row[n];
  int cend = (cnt + (pad16 ? 15 : 0)) & ~15;
  float ysk = ys2[n*D+k];
  float gacc = 0.f;
  int i = 0;
  for (; i < cend; i += 16){
    int   ce = row_dst[base+i+k];
    float we = row_w[base+i+k];
    float myg = 0.f;
    #pragma unroll
    for (int j = 0; j < 16; j++){
      int   cj = __shfl(ce, j, 16);
      float wj = __shfl(we, j, 16);
      float dval = ds3[cj*D+k];
      gacc += wj*dval;
      float p = red16(dval*ysk);
      if (j == k) myg = p;
    }
    gn_row[base+i+k] = myg;          // coalesced store
  }
  for (; i < cnt; i++){
    int c = row_dst[base+i];
    float dval = ds3[c*D+k];
    gacc += row_w[base+i]*dval;
    float p = red16(dval*ysk);
    if (k == 0) gn_row[base+i] = p;
  }
  float dv = dinv[n];
  unsigned m = masks[n];
  float gy = dv*gacc + dv*ds3[n*D+k];      // gy2 + d2*du3
  float du2 = 0.f;
  #pragma unroll
  for (int j = 0; j < D; j++) du2 += __shfl(gy, j, 16)*sW2[k*D+j];
  du2 *= ((m>>(16+k))&1u) ? 1.0f : SLOPE;
  float du1 = 0.f;
  #pragma unroll
  for (int j = 0; j < D; j++) du1 += __shfl(du2, j, 16)*sWl1[k*D+j];
  du1 *= ((m>>k)&1u) ? 1.0f : SLOPE;
  float gd = red16(du1*ys1[n*D+k]);        // adds dv*(du1 . y1)
  if (k == 0) gdiag[n] += gd;
  ds1[n*D+k] = dv*du1;
}

// row pass 1: gn_row += ds1[c].ys1[n]; gdinv_row = sum gn*w (pad: w=0 kills it)
__global__ void k_bwd1row(const int* __restrict__ row_dst, const float* __restrict__ row_w,
                          const int* __restrict__ off_row, const int* __restrict__ cnt_row,
                          const float* __restrict__ ys1, const float* __restrict__ ds1,
                          float* __restrict__ gn_row, float* __restrict__ gdinv_row,
                          int pad16){
  int t = blockIdx.x*blockDim.x + threadIdx.x;
  int n = t >> 4, k = t & 15;
  if (n >= NN) return;
  int base = pad16 ? n*CAP : off_row[n];
  int cnt = cnt_row[n];
  int cend = (cnt + (pad16 ? 15 : 0)) & ~15;
  float ysk = ys1[n*D+k];
  float gdr = 0.f;
  int i = 0;
  for (; i < cend; i += 16){
    int   ce = row_dst[base+i+k];
    float we = row_w[base+i+k];
    float gold = gn_row[base+i+k];   // coalesced read
    float myg = 0.f;
    #pragma unroll
    for (int j = 0; j < 16; j++){
      int   cj = __shfl(ce, j, 16);
      float wj = __shfl(we, j, 16);
      float dval = ds1[cj*D+k];
      float p = red16(dval*ysk);
      float gj = __shfl(gold, j, 16) + p;
      if (j == k) myg = gj;
      gdr += gj*wj;
    }
    gn_row[base+i+k] = myg;          // coalesced store
  }
  for (; i < cnt; i++){
    int c = row_dst[base+i];
    float dval = ds1[c*D+k];
    float p = red16(dval*ysk);
    float g = gn_row[base+i] + p;
    if (k == 0) gn_row[base+i] = g;
    gdr += g*row_w[base+i];
  }
  if (k == 0) gdinv_row[n] = gdr;
}

// col pass: gns_col copy (contiguous write), gdeg, packed node table (pos, gdeg)
__global__ void k_gdeg(const int* __restrict__ col_rp, const float* __restrict__ col_w,
                       const int* __restrict__ off_col, const int* __restrict__ cnt_col,
                       const float* __restrict__ gn_row, const float* __restrict__ gdinv_row,
                       const float* __restrict__ gdiag, const float* __restrict__ dinv,
                       const float4* __restrict__ pos4,
                       float* __restrict__ gns_col, float4* __restrict__ pn4, int pad16){
  int t = blockIdx.x*blockDim.x + threadIdx.x;
  int n = t >> 4, k = t & 15;
  if (n >= NN) return;
  int base = pad16 ? n*CAP : off_col[n];
  int cnt = cnt_col[n];
  float gc = 0.f;
  for (int i = k; i < cnt; i += 16){
    float g = gn_row[col_rp[base+i]];
    gc += g*col_w[base+i];
    gns_col[base+i] = g;
  }
  gc = red16(gc);
  if (k == 0){
    float dv = dinv[n];
    float arg = (gdinv_row[n] + gc)/dv + 2.0f*gdiag[n];  // gdiag holds dv*gdiag_true
    float gd = -0.5f*dv*dv*dv*arg;
    float4 p = pos4[n];
    pn4[n] = make_float4(p.x, p.y, p.z, gd);
  }
}

// force gather: coef = (gns + gdeg[col-node])/w, both directions (true cnt only)
__global__ void k_force(const int* __restrict__ row_dst, const float* __restrict__ row_w,
                        const int* __restrict__ off_row, const int* __restrict__ cnt_row,
                        const int* __restrict__ col_si, const float* __restrict__ col_w,
                        const int* __restrict__ off_col, const int* __restrict__ cnt_col,
                        const float* __restrict__ gn_row, const float* __restrict__ gns_col,
                        const float4* __restrict__ pn4, float* __restrict__ F, int pad16){
  int t = blockIdx.x*blockDim.x + threadIdx.x;
  int n = t >> 4, k = t & 15;
  if (n >= NN) return;
  float4 pn = pn4[n];
  float fx = 0.f, fy = 0.f, fz = 0.f;
  int base = pad16 ? n*CAP : off_row[n];
  int cnt = cnt_row[n];
  for (int i = k; i < cnt; i += 16){
    int c = row_dst[base+i];
    float g = gn_row[base+i];
    float4 pc = pn4[c];
    float coef = (g + pc.w)/row_w[base+i];
    fx -= coef*(pn.x-pc.x); fy -= coef*(pn.y-pc.y); fz -= coef*(pn.z-pc.z);
  }
  base = pad16 ? n*CAP : off_col[n];
  cnt = cnt_col[n];
  for (int i = k; i < cnt; i += 16){
    int r = col_si[base+i];
    if (pad16) r /= CAP;
    float g = gns_col[base+i];
    float4 pr = pn4[r];
    float coef = (g + pn.w)/col_w[base+i];
    fx += coef*(pr.x-pn.x); fy += coef*(pr.y-pn.y); fz += coef*(pr.z-pn.z);
  }
  fx = red16(fx); fy = red16(fy); fz = red16(fz);
  if (k == 0){ F[3*n+0] = fx; F[3*n+1] = fy; F[3*n+2] = fz; }
}

extern "C" void kernel_launch(void* const* d_in, const int* in_sizes, int n_in,
                              void* d_out, int out_size, void* d_ws, size_t ws_size,
                              hipStream_t stream){
  const float* pos = (const float*)d_in[0];
  const float* emb = (const float*)d_in[1];
  const float* W1  = (const float*)d_in[2];
  const float* b1  = (const float*)d_in[3];
  const float* Wl1 = (const float*)d_in[4];
  const float* bl1 = (const float*)d_in[5];
  const float* W2  = (const float*)d_in[6];
  const float* b2  = (const float*)d_in[7];
  const float* Wl2 = (const float*)d_in[8];
  const float* bl2 = (const float*)d_in[9];
  const float* Wl3 = (const float*)d_in[10];
  const float* bl3 = (const float*)d_in[11];
  const int* z     = (const int*)d_in[12];
  const int* ei    = (const int*)d_in[13];
  const int* batch = (const int*)d_in[14];

  // padded layout: ~78N + 1024 + 6*CAP*N words (~224 MB); gate on ws_size
  size_t need_pad = 4ull*((size_t)78*NN + 1024 + 6ull*CAP*NN);
  bool padded = (ws_size >= need_pad);
  size_t ER = padded ? (size_t)CAP*NN : (size_t)NE;
  int pad16 = padded ? 1 : 0;

  char* base = (char*)d_ws;
  size_t o = 0;
  auto alloc = [&](size_t words){ o = (o + 15) & ~(size_t)15; void* p = base + o*4; o += words; return p; };
  int*   cnt_row   = (int*)alloc(NN);
  int*   cnt_col   = (int*)alloc(NN);
  int*   off_row   = (int*)alloc(NN);
  int*   off_col   = (int*)alloc(NN);
  int*   cur_row   = (int*)alloc(NN);
  int*   cur_col   = (int*)alloc(NN);
  int*   bsum      = (int*)alloc(1024);
  float* dinv      = (float*)alloc(NN);
  float* gdiag     = (float*)alloc(NN);
  float* gdinv_row = (float*)alloc(NN);
  unsigned* masks  = (unsigned*)alloc(NN);
  float4* pos4     = (float4*)alloc(4*NN);
  float* ys1       = (float*)alloc(16*NN);
  float* ys2       = (float*)alloc(16*NN);
  float* ds3       = (float*)alloc(16*NN);
  float* ds1       = (float*)alloc(16*NN);
  int*   row_dst   = (int*)alloc(ER);
  float* row_w     = (float*)alloc(ER);
  int*   col_rp    = (int*)alloc(ER);
  float* col_w     = (float*)alloc(ER);
  float* gn_row    = (float*)alloc(ER);
  int*   col_src   = padded ? nullptr : (int*)alloc(NE);   // compact only
  float* gns_col   = padded ? (float*)alloc(ER) : ys1;     // compact aliases ys1+ys2
  float4* pn4      = (float4*)ds3;                          // dead after bwd2mid
  // col_si: the array consumers derive src from
  const int* col_si = padded ? col_rp : col_src;

  float* Eout = (float*)d_out;
  float* F = Eout + NG;

  int nbN   = (NN + BT - 1)/BT;        // 391
  int nbE   = (NE + BT - 1)/BT;
  int nbE4  = (NE/4 + BT - 1)/BT;
  int nbN16 = (NN*16 + BT - 1)/BT;     // 6250

  hipMemsetAsync(cnt_row, 0, 2*(size_t)NN*4, stream);
  hipMemsetAsync(Eout, 0, (size_t)NG*4, stream);

  k_pos4<<<nbN, BT, 0, stream>>>(pos, pos4);

  // CSR build
  if (padded){
    k_place_pad<<<nbE, BT, 0, stream>>>(ei, pos4, cnt_row, cnt_col,
                                        row_dst, row_w, col_rp, col_w);
    k_padzero<<<nbN16, BT, 0, stream>>>(cnt_row, cnt_col,
                                        row_dst, row_w, col_rp, col_w);
  } else {
    k_count<<<nbE4, BT, 0, stream>>>(ei, cnt_row, cnt_col);
    k_blocksum<<<dim3(nbN,2), BT, 0, stream>>>(cnt_row, cnt_col, bsum);
    k_scan_bsum<<<dim3(1,2), 512, 0, stream>>>(bsum, nbN);
    k_offsets<<<dim3(nbN,2), BT, 0, stream>>>(cnt_row, cnt_col, bsum,
                                              off_row, off_col, cur_row, cur_col);
    k_place<<<nbE, BT, 0, stream>>>(ei, pos4, cur_row, cur_col,
                                    row_dst, row_w, col_src, col_rp, col_w);
  }

  // forward
  k_dinv_y1<<<nbN16, BT, 0, stream>>>(col_w, off_col, cnt_col, emb, z, W1,
                                      dinv, ys1, pad16);
  k_conv1_mid<<<nbN16, BT, 0, stream>>>(col_si, col_w, off_col, cnt_col, dinv, ys1,
                                        b1, Wl1, bl1, W2, ys2, masks, pad16);
  k_conv2_out<<<nbN16, BT, 0, stream>>>(col_si, col_w, off_col, cnt_col, dinv, ys2,
                                        batch, b2, Wl2, bl2, Wl3, bl3, Eout, ds3,
                                        gdiag, pad16);

  // backward
  k_bwd2mid<<<nbN16, BT, 0, stream>>>(row_dst, row_w, off_row, cnt_row, dinv, ys1, ys2,
                                      ds3, masks, W2, Wl1, gn_row, ds1, gdiag, pad16);
  k_bwd1row<<<nbN16, BT, 0, stream>>>(row_dst, row_w, off_row, cnt_row, ys1, ds1,
                                      gn_row, gdinv_row, pad16);
  k_gdeg<<<nbN16, BT, 0, stream>>>(col_rp, col_w, off_col, cnt_col, gn_row, gdinv_row,
                                   gdiag, dinv, pos4, gns_col, pn4, pad16);
  k_force<<<nbN16, BT, 0, stream>>>(row_dst, row_w, off_row, cnt_row,
                                    col_si, col_w, off_col, cnt_col,
                                    gn_row, gns_col, pn4, F, pad16);
}

// Round 10
// 866.542 us; speedup vs baseline: 1.1385x; 1.1385x over previous
//
#include <hip/hip_runtime.h>
#include <math.h>

#define NN 100000
#define NE 3200000
#define NG 512
#define D 16
#define SLOPE 0.01f
#define BT 256
#define CAP 80   // padded-CSR slots per node (mean deg 32, exp. max ~60); CAP%16==0

__device__ __forceinline__ float leakyf(float x){ return x >= 0.0f ? x : SLOPE*x; }
__device__ __forceinline__ float dleakyf(float x){ return x >= 0.0f ? 1.0f : SLOPE; }

__device__ __forceinline__ float red16(float v){
  v += __shfl_xor(v, 8, 16);
  v += __shfl_xor(v, 4, 16);
  v += __shfl_xor(v, 2, 16);
  v += __shfl_xor(v, 1, 16);
  return v;
}

// fused: pos repack + analytic padded offsets
__global__ void k_pos4_off(const float* __restrict__ pos, float4* __restrict__ pos4,
                           int* __restrict__ off_row, int* __restrict__ off_col,
                           int use_pad){
  int n = blockIdx.x*blockDim.x + threadIdx.x;
  if (n >= NN) return;
  pos4[n] = make_float4(pos[3*n+0], pos[3*n+1], pos[3*n+2], 0.0f);
  if (use_pad){ off_row[n] = n*CAP; off_col[n] = n*CAP; }
}

// ---- CSR build, compact path (count + scan + place) ----------------------
__global__ void k_count(const int* __restrict__ ei, int* __restrict__ cnt_row,
                        int* __restrict__ cnt_col){
  int t = blockIdx.x*blockDim.x + threadIdx.x;
  if (t >= NE/4) return;
  int4 r4 = ((const int4*)ei)[t];
  int4 c4 = ((const int4*)(ei + NE))[t];
  atomicAdd(&cnt_row[r4.x], 1); atomicAdd(&cnt_row[r4.y], 1);
  atomicAdd(&cnt_row[r4.z], 1); atomicAdd(&cnt_row[r4.w], 1);
  atomicAdd(&cnt_col[c4.x], 1); atomicAdd(&cnt_col[c4.y], 1);
  atomicAdd(&cnt_col[c4.z], 1); atomicAdd(&cnt_col[c4.w], 1);
}

__global__ void k_blocksum(const int* __restrict__ cnt_row, const int* __restrict__ cnt_col,
                           int* __restrict__ bsum){
  const int* src = blockIdx.y ? cnt_col : cnt_row;
  __shared__ int s[BT];
  int i = blockIdx.x*BT + threadIdx.x;
  s[threadIdx.x] = (i < NN) ? src[i] : 0;
  __syncthreads();
  for (int off = BT/2; off > 0; off >>= 1){
    if (threadIdx.x < off) s[threadIdx.x] += s[threadIdx.x+off];
    __syncthreads();
  }
  if (threadIdx.x == 0) bsum[blockIdx.y*512 + blockIdx.x] = s[0];
}

__global__ void k_scan_bsum(int* __restrict__ bsum, int nb){
  int* b = bsum + blockIdx.y*512;
  __shared__ int s0[512], s1[512];
  int tid = threadIdx.x;
  int v = (tid < nb) ? b[tid] : 0;
  s0[tid] = v; __syncthreads();
  int rd = 0;
  for (int off = 1; off < 512; off <<= 1){
    int x = rd ? s1[tid] : s0[tid];
    if (tid >= off) x += rd ? s1[tid-off] : s0[tid-off];
    if (rd) s0[tid] = x; else s1[tid] = x;
    __syncthreads();
    rd ^= 1;
  }
  int incl = rd ? s1[tid] : s0[tid];
  if (tid < nb) b[tid] = incl - v;
}

__global__ void k_offsets(const int* __restrict__ cnt_row, const int* __restrict__ cnt_col,
                          const int* __restrict__ bsum,
                          int* __restrict__ off_row, int* __restrict__ off_col,
                          int* __restrict__ cur_row, int* __restrict__ cur_col){
  const int* src  = blockIdx.y ? cnt_col : cnt_row;
  int* offd = blockIdx.y ? off_col : off_row;
  int* curd = blockIdx.y ? cur_col : cur_row;
  __shared__ int s0[BT], s1[BT];
  int tid = threadIdx.x;
  int i = blockIdx.x*BT + tid;
  int v = (i < NN) ? src[i] : 0;
  s0[tid] = v; __syncthreads();
  int rd = 0;
  for (int off = 1; off < BT; off <<= 1){
    int x = rd ? s1[tid] : s0[tid];
    if (tid >= off) x += rd ? s1[tid-off] : s0[tid-off];
    if (rd) s0[tid] = x; else s1[tid] = x;
    __syncthreads();
    rd ^= 1;
  }
  int incl = rd ? s1[tid] : s0[tid];
  if (i < NN){
    int o = bsum[blockIdx.y*512 + blockIdx.x] + incl - v;
    offd[i] = o; curd[i] = o;
  }
}

// SoA scattered 4B stores (measured fastest layout: r2 vs r3 AoS, r8 vs r9 drop)
__global__ void k_place(const int* __restrict__ ei, const float4* __restrict__ pos4,
                        int* __restrict__ cur_row, int* __restrict__ cur_col,
                        int* __restrict__ row_dst, float* __restrict__ row_w,
                        int* __restrict__ col_src, int* __restrict__ col_rp,
                        float* __restrict__ col_w){
  int e = blockIdx.x*blockDim.x + threadIdx.x;
  if (e >= NE) return;
  int r = ei[e], c = ei[NE+e];
  float4 pr = pos4[r], pc = pos4[c];
  float dx = pr.x-pc.x, dy = pr.y-pc.y, dz = pr.z-pc.z;
  float w = sqrtf(dx*dx+dy*dy+dz*dz);
  int p = atomicAdd(&cur_row[r], 1);
  int q = atomicAdd(&cur_col[c], 1);
  row_dst[p] = c; row_w[p] = w;
  col_src[q] = r; col_rp[q] = p; col_w[q] = w;
}

// ---- CSR build, padded path (no count/scan; base = n*CAP) ----------------
__global__ void k_place_pad(const int* __restrict__ ei, const float4* __restrict__ pos4,
                            int* __restrict__ cnt_row, int* __restrict__ cnt_col,
                            int* __restrict__ row_dst, float* __restrict__ row_w,
                            int* __restrict__ col_src, int* __restrict__ col_rp,
                            float* __restrict__ col_w){
  int e = blockIdx.x*blockDim.x + threadIdx.x;
  if (e >= NE) return;
  int r = ei[e], c = ei[NE+e];
  float4 pr = pos4[r], pc = pos4[c];
  float dx = pr.x-pc.x, dy = pr.y-pc.y, dz = pr.z-pc.z;
  float w = sqrtf(dx*dx+dy*dy+dz*dz);
  int p = r*CAP + atomicAdd(&cnt_row[r], 1);
  int q = c*CAP + atomicAdd(&cnt_col[c], 1);
  row_dst[p] = c; row_w[p] = w;
  col_src[q] = r; col_rp[q] = p; col_w[q] = w;
}

// zero-fill pad slots [cnt, roundup16(cnt)) so block loops can skip tails.
// src/dst=0 (valid index), w=0 (nullifies every weighted contribution).
__global__ void k_padzero(const int* __restrict__ cnt_row, const int* __restrict__ cnt_col,
                          int* __restrict__ row_dst, float* __restrict__ row_w,
                          int* __restrict__ col_src, float* __restrict__ col_w){
  int t = blockIdx.x*blockDim.x + threadIdx.x;
  int n = t >> 4, k = t & 15;
  if (n >= NN) return;
  int cr = cnt_row[n], er = (cr + 15) & ~15;
  if (cr + k < er){ row_dst[n*CAP + cr + k] = 0; row_w[n*CAP + cr + k] = 0.f; }
  int cc = cnt_col[n], ec = (cc + 15) & ~15;
  if (cc + k < ec){ col_src[n*CAP + cc + k] = 0; col_w[n*CAP + cc + k] = 0.f; }
}

// ---- forward ------------------------------------------------------------
__global__ void k_dinv_y1(const float* __restrict__ col_w, const int* __restrict__ off_col,
                          const int* __restrict__ cnt_col,
                          const float* __restrict__ emb, const int* __restrict__ z,
                          const float* __restrict__ W1,
                          float* __restrict__ dinv, float* __restrict__ ys1){
  __shared__ float sW[D*D];
  for (int i = threadIdx.x; i < D*D; i += blockDim.x) sW[i] = W1[i];
  __syncthreads();
  int t = blockIdx.x*blockDim.x + threadIdx.x;
  int n = t >> 4, k = t & 15;
  if (n >= NN) return;
  int base = off_col[n], cnt = cnt_col[n];
  float s = 0.f;
  for (int i = k; i < cnt; i += 16) s += col_w[base+i];
  s = red16(s);
  float dv = 1.0f / sqrtf(1.0f + s);
  if (k == 0) dinv[n] = dv;
  float h = emb[z[n]*D + k];
  float acc = 0.f;
  #pragma unroll
  for (int j = 0; j < D; j++) acc += __shfl(h, j, 16)*sW[j*D+k];
  ys1[n*D+k] = dv*acc;
}

// conv1 gather (16-edge blocks; pad16 -> no tail) + MLP mid
__global__ void k_conv1_mid(const int* __restrict__ col_src, const float* __restrict__ col_w,
                            const int* __restrict__ off_col, const int* __restrict__ cnt_col,
                            const float* __restrict__ dinv, const float* __restrict__ ys1,
                            const float* __restrict__ b1, const float* __restrict__ Wl1,
                            const float* __restrict__ bl1, const float* __restrict__ W2,
                            float* __restrict__ ys2, unsigned* __restrict__ masks,
                            int pad16){
  __shared__ float sWl1[D*D], sW2[D*D], sb1[D], sbl1[D];
  for (int i = threadIdx.x; i < D*D; i += blockDim.x){ sWl1[i] = Wl1[i]; sW2[i] = W2[i]; }
  if (threadIdx.x < D){ sb1[threadIdx.x] = b1[threadIdx.x]; sbl1[threadIdx.x] = bl1[threadIdx.x]; }
  __syncthreads();
  int t = blockIdx.x*blockDim.x + threadIdx.x;
  int n = t >> 4, k = t & 15;
  if (n >= NN) return;
  int base = off_col[n], cnt = cnt_col[n];
  int cend = (cnt + (pad16 ? 15 : 0)) & ~15;
  float acc = 0.f;
  int i = 0;
  for (; i < cend; i += 16){
    int   se = col_src[base+i+k];   // coalesced: 16 lanes, 16 consecutive edges
    float we = col_w[base+i+k];
    #pragma unroll
    for (int j = 0; j < 16; j++){
      int   sj = __shfl(se, j, 16);
      float wj = __shfl(we, j, 16);
      acc += wj * ys1[sj*D+k];
    }
  }
  for (; i < cnt; i++)
    acc += col_w[base+i]*ys1[col_src[base+i]*D+k];
  float dv = dinv[n];
  float u1 = dv*(acc + ys1[n*D+k]) + sb1[k];
  float h1 = leakyf(u1);
  float u2 = sbl1[k];
  #pragma unroll
  for (int j = 0; j < D; j++) u2 += __shfl(h1, j, 16)*sWl1[j*D+k];
  float h2 = leakyf(u2);
  float yo = 0.f;
  #pragma unroll
  for (int j = 0; j < D; j++) yo += __shfl(h2, j, 16)*sW2[j*D+k];
  ys2[n*D+k] = dv*yo;
  unsigned mm = ((u1 >= 0.f) ? (1u<<k) : 0u) | ((u2 >= 0.f) ? (1u<<(16+k)) : 0u);
  mm |= (unsigned)__shfl_xor((int)mm, 8, 16);
  mm |= (unsigned)__shfl_xor((int)mm, 4, 16);
  mm |= (unsigned)__shfl_xor((int)mm, 2, 16);
  mm |= (unsigned)__shfl_xor((int)mm, 1, 16);
  if (k == 0) masks[n] = mm;
}

// conv2 gather (16-edge blocks) + head + energy + head backward: ds3, gdiag_s
__global__ void k_conv2_out(const int* __restrict__ col_src, const float* __restrict__ col_w,
                            const int* __restrict__ off_col, const int* __restrict__ cnt_col,
                            const float* __restrict__ dinv, const float* __restrict__ ys2,
                            const int* __restrict__ batch,
                            const float* __restrict__ b2, const float* __restrict__ Wl2,
                            const float* __restrict__ bl2, const float* __restrict__ Wl3,
                            const float* __restrict__ bl3,
                            float* __restrict__ Eout, float* __restrict__ ds3,
                            float* __restrict__ gdiag, int pad16){
  __shared__ float sWl2[D*4], sb2[D], sbl2[4], sWl3[4], sbl3s;
  if (threadIdx.x < D*4) sWl2[threadIdx.x] = Wl2[threadIdx.x];
  if (threadIdx.x < D) sb2[threadIdx.x] = b2[threadIdx.x];
  if (threadIdx.x < 4){ sbl2[threadIdx.x] = bl2[threadIdx.x]; sWl3[threadIdx.x] = Wl3[threadIdx.x]; }
  if (threadIdx.x == 0) sbl3s = bl3[0];
  __syncthreads();
  int t = blockIdx.x*blockDim.x + threadIdx.x;
  int n = t >> 4, k = t & 15;
  if (n >= NN) return;
  int base = off_col[n], cnt = cnt_col[n];
  int cend = (cnt + (pad16 ? 15 : 0)) & ~15;
  float acc = 0.f;
  int i = 0;
  for (; i < cend; i += 16){
    int   se = col_src[base+i+k];
    float we = col_w[base+i+k];
    #pragma unroll
    for (int j = 0; j < 16; j++){
      int   sj = __shfl(se, j, 16);
      float wj = __shfl(we, j, 16);
      acc += wj * ys2[sj*D+k];
    }
  }
  for (; i < cnt; i++)
    acc += col_w[base+i]*ys2[col_src[base+i]*D+k];
  float dv = dinv[n];
  float ysk = ys2[n*D+k];
  float u3 = dv*(acc + ysk) + sb2[k];
  float h3 = leakyf(u3);
  float u40 = sbl2[0], u41 = sbl2[1], u42 = sbl2[2], u43 = sbl2[3];
  #pragma unroll
  for (int j = 0; j < D; j++){
    float hj = __shfl(h3, j, 16);
    u40 += hj*sWl2[j*4+0]; u41 += hj*sWl2[j*4+1];
    u42 += hj*sWl2[j*4+2]; u43 += hj*sWl2[j*4+3];
  }
  float h40 = leakyf(u40), h41 = leakyf(u41), h42 = leakyf(u42), h43 = leakyf(u43);
  float u5 = sbl3s + h40*sWl3[0] + h41*sWl3[1] + h42*sWl3[2] + h43*sWl3[3];
  float h5 = leakyf(u5);
  if (k == 0) atomicAdd(&Eout[batch[n]], h5);
  float du5 = dleakyf(u5);
  float d40 = du5*sWl3[0]*dleakyf(u40);
  float d41 = du5*sWl3[1]*dleakyf(u41);
  float d42 = du5*sWl3[2]*dleakyf(u42);
  float d43 = du5*sWl3[3]*dleakyf(u43);
  float g = d40*sWl2[k*4+0] + d41*sWl2[k*4+1] + d42*sWl2[k*4+2] + d43*sWl2[k*4+3];
  float d3 = g*dleakyf(u3);
  ds3[n*D+k] = dv*d3;
  float gd = red16(d3*ysk);          // gdiag_s = dv * (du3 . y2)
  if (k == 0) gdiag[n] = gd;
}

// ---- backward -----------------------------------------------------------
// FUSED row pass 2 + node mid chain. Pad-slot gn writes are finite garbage,
// only ever multiplied by w=0 downstream.
__global__ void k_bwd2mid(const int* __restrict__ row_dst, const float* __restrict__ row_w,
                          const int* __restrict__ off_row, const int* __restrict__ cnt_row,
                          const float* __restrict__ dinv, const float* __restrict__ ys1,
                          const float* __restrict__ ys2, const float* __restrict__ ds3,
                          const unsigned* __restrict__ masks,
                          const float* __restrict__ W2, const float* __restrict__ Wl1,
                          float* __restrict__ gn_row, float* __restrict__ ds1,
                          float* __restrict__ gdiag, int pad16){
  __shared__ float sW2[D*D], sWl1[D*D];
  for (int i = threadIdx.x; i < D*D; i += blockDim.x){ sW2[i] = W2[i]; sWl1[i] = Wl1[i]; }
  __syncthreads();
  int t = blockIdx.x*blockDim.x + threadIdx.x;
  int n = t >> 4, k = t & 15;
  if (n >= NN) return;
  int base = off_row[n], cnt = cnt_row[n];
  int cend = (cnt + (pad16 ? 15 : 0)) & ~15;
  float ysk = ys2[n*D+k];
  float gacc = 0.f;
  int i = 0;
  for (; i < cend; i += 16){
    int   ce = row_dst[base+i+k];
    float we = row_w[base+i+k];
    float myg = 0.f;
    #pragma unroll
    for (int j = 0; j < 16; j++){
      int   cj = __shfl(ce, j, 16);
      float wj = __shfl(we, j, 16);
      float dval = ds3[cj*D+k];
      gacc += wj*dval;
      float p = red16(dval*ysk);
      if (j == k) myg = p;
    }
    gn_row[base+i+k] = myg;          // coalesced store
  }
  for (; i < cnt; i++){
    int c = row_dst[base+i];
    float dval = ds3[c*D+k];
    gacc += row_w[base+i]*dval;
    float p = red16(dval*ysk);
    if (k == 0) gn_row[base+i] = p;
  }
  float dv = dinv[n];
  unsigned m = masks[n];
  float gy = dv*gacc + dv*ds3[n*D+k];      // gy2 + d2*du3
  float du2 = 0.f;
  #pragma unroll
  for (int j = 0; j < D; j++) du2 += __shfl(gy, j, 16)*sW2[k*D+j];
  du2 *= ((m>>(16+k))&1u) ? 1.0f : SLOPE;
  float du1 = 0.f;
  #pragma unroll
  for (int j = 0; j < D; j++) du1 += __shfl(du2, j, 16)*sWl1[k*D+j];
  du1 *= ((m>>k)&1u) ? 1.0f : SLOPE;
  float gd = red16(du1*ys1[n*D+k]);        // adds dv*(du1 . y1)
  if (k == 0) gdiag[n] += gd;
  ds1[n*D+k] = dv*du1;
}

// row pass 1: gn_row += ds1[c].ys1[n]; gdinv_row = sum gn*w (pad: w=0 kills it)
__global__ void k_bwd1row(const int* __restrict__ row_dst, const float* __restrict__ row_w,
                          const int* __restrict__ off_row, const int* __restrict__ cnt_row,
                          const float* __restrict__ ys1, const float* __restrict__ ds1,
                          float* __restrict__ gn_row, float* __restrict__ gdinv_row,
                          int pad16){
  int t = blockIdx.x*blockDim.x + threadIdx.x;
  int n = t >> 4, k = t & 15;
  if (n >= NN) return;
  int base = off_row[n], cnt = cnt_row[n];
  int cend = (cnt + (pad16 ? 15 : 0)) & ~15;
  float ysk = ys1[n*D+k];
  float gdr = 0.f;
  int i = 0;
  for (; i < cend; i += 16){
    int   ce = row_dst[base+i+k];
    float we = row_w[base+i+k];
    float gold = gn_row[base+i+k];   // coalesced read
    float myg = 0.f;
    #pragma unroll
    for (int j = 0; j < 16; j++){
      int   cj = __shfl(ce, j, 16);
      float wj = __shfl(we, j, 16);
      float dval = ds1[cj*D+k];
      float p = red16(dval*ysk);
      float gj = __shfl(gold, j, 16) + p;
      if (j == k) myg = gj;
      gdr += gj*wj;
    }
    gn_row[base+i+k] = myg;          // coalesced store
  }
  for (; i < cnt; i++){
    int c = row_dst[base+i];
    float dval = ds1[c*D+k];
    float p = red16(dval*ysk);
    float g = gn_row[base+i] + p;
    if (k == 0) gn_row[base+i] = g;
    gdr += g*row_w[base+i];
  }
  if (k == 0) gdinv_row[n] = gdr;
}

// col pass: gns_col copy (contiguous write), gdeg, packed node table (pos, gdeg)
__global__ void k_gdeg(const int* __restrict__ col_rp, const float* __restrict__ col_w,
                       const int* __restrict__ off_col, const int* __restrict__ cnt_col,
                       const float* __restrict__ gn_row, const float* __restrict__ gdinv_row,
                       const float* __restrict__ gdiag, const float* __restrict__ dinv,
                       const float4* __restrict__ pos4,
                       float* __restrict__ gns_col, float4* __restrict__ pn4){
  int t = blockIdx.x*blockDim.x + threadIdx.x;
  int n = t >> 4, k = t & 15;
  if (n >= NN) return;
  int base = off_col[n], cnt = cnt_col[n];
  float gc = 0.f;
  for (int i = k; i < cnt; i += 16){
    float g = gn_row[col_rp[base+i]];
    gc += g*col_w[base+i];
    gns_col[base+i] = g;
  }
  gc = red16(gc);
  if (k == 0){
    float dv = dinv[n];
    float arg = (gdinv_row[n] + gc)/dv + 2.0f*gdiag[n];  // gdiag holds dv*gdiag_true
    float gd = -0.5f*dv*dv*dv*arg;
    float4 p = pos4[n];
    pn4[n] = make_float4(p.x, p.y, p.z, gd);
  }
}

// force gather: coef = (gns + gdeg[col-node])/w, both directions (true cnt only)
__global__ void k_force(const int* __restrict__ row_dst, const float* __restrict__ row_w,
                        const int* __restrict__ off_row, const int* __restrict__ cnt_row,
                        const int* __restrict__ col_src, const float* __restrict__ col_w,
                        const int* __restrict__ off_col, const int* __restrict__ cnt_col,
                        const float* __restrict__ gn_row, const float* __restrict__ gns_col,
                        const float4* __restrict__ pn4, float* __restrict__ F){
  int t = blockIdx.x*blockDim.x + threadIdx.x;
  int n = t >> 4, k = t & 15;
  if (n >= NN) return;
  float4 pn = pn4[n];
  float fx = 0.f, fy = 0.f, fz = 0.f;
  int base = off_row[n], cnt = cnt_row[n];
  for (int i = k; i < cnt; i += 16){
    int c = row_dst[base+i];
    float g = gn_row[base+i];
    float4 pc = pn4[c];
    float coef = (g + pc.w)/row_w[base+i];
    fx -= coef*(pn.x-pc.x); fy -= coef*(pn.y-pc.y); fz -= coef*(pn.z-pc.z);
  }
  base = off_col[n]; cnt = cnt_col[n];
  for (int i = k; i < cnt; i += 16){
    int r = col_src[base+i];
    float g = gns_col[base+i];
    float4 pr = pn4[r];
    float coef = (g + pn.w)/col_w[base+i];
    fx += coef*(pr.x-pn.x); fy += coef*(pr.y-pn.y); fz += coef*(pr.z-pn.z);
  }
  fx = red16(fx); fy = red16(fy); fz = red16(fz);
  if (k == 0){ F[3*n+0] = fx; F[3*n+1] = fy; F[3*n+2] = fz; }
}

extern "C" void kernel_launch(void* const* d_in, const int* in_sizes, int n_in,
                              void* d_out, int out_size, void* d_ws, size_t ws_size,
                              hipStream_t stream){
  const float* pos = (const float*)d_in[0];
  const float* emb = (const float*)d_in[1];
  const float* W1  = (const float*)d_in[2];
  const float* b1  = (const float*)d_in[3];
  const float* Wl1 = (const float*)d_in[4];
  const float* bl1 = (const float*)d_in[5];
  const float* W2  = (const float*)d_in[6];
  const float* b2  = (const float*)d_in[7];
  const float* Wl2 = (const float*)d_in[8];
  const float* bl2 = (const float*)d_in[9];
  const float* Wl3 = (const float*)d_in[10];
  const float* bl3 = (const float*)d_in[11];
  const int* z     = (const int*)d_in[12];
  const int* ei    = (const int*)d_in[13];
  const int* batch = (const int*)d_in[14];

  // padded layout needs ~78N + 1024 + 7*CAP*N words (~255 MB); gate on ws_size
  size_t need_pad = 4ull*((size_t)78*NN + 1024 + 7ull*CAP*NN);
  bool padded = (ws_size >= need_pad);
  size_t ER = padded ? (size_t)CAP*NN : (size_t)NE;   // edge-array length
  int pad16 = padded ? 1 : 0;

  char* base = (char*)d_ws;
  size_t o = 0;
  auto alloc = [&](size_t words){ o = (o + 15) & ~(size_t)15; void* p = base + o*4; o += words; return p; };
  int*   cnt_row   = (int*)alloc(NN);
  int*   cnt_col   = (int*)alloc(NN);
  int*   off_row   = (int*)alloc(NN);
  int*   off_col   = (int*)alloc(NN);
  int*   cur_row   = (int*)alloc(NN);
  int*   cur_col   = (int*)alloc(NN);
  int*   bsum      = (int*)alloc(1024);
  float* dinv      = (float*)alloc(NN);
  float* gdiag     = (float*)alloc(NN);
  float* gdinv_row = (float*)alloc(NN);
  unsigned* masks  = (unsigned*)alloc(NN);
  float4* pos4     = (float4*)alloc(4*NN);
  float* ys1       = (float*)alloc(16*NN);
  float* ys2       = (float*)alloc(16*NN);
  float* ds3       = (float*)alloc(16*NN);
  float* ds1       = (float*)alloc(16*NN);
  int*   row_dst   = (int*)alloc(ER);
  float* row_w     = (float*)alloc(ER);
  int*   col_src   = (int*)alloc(ER);
  int*   col_rp    = (int*)alloc(ER);
  float* col_w     = (float*)alloc(ER);
  float* gn_row    = (float*)alloc(ER);
  // gns_col: padded path allocates; compact path aliases ys1+ys2 (E == 32N,
  // both dead after k_bwd1row). pn4 aliases ds3 (dead after k_bwd2mid).
  float*  gns_col = padded ? (float*)alloc(ER) : ys1;
  float4* pn4     = (float4*)ds3;

  float* Eout = (float*)d_out;
  float* F = Eout + NG;

  int nbN   = (NN + BT - 1)/BT;        // 391
  int nbE   = (NE + BT - 1)/BT;
  int nbE4  = (NE/4 + BT - 1)/BT;
  int nbN16 = (NN*16 + BT - 1)/BT;     // 6250

  hipMemsetAsync(cnt_row, 0, 2*(size_t)NN*4, stream);
  hipMemsetAsync(Eout, 0, (size_t)NG*4, stream);

  k_pos4_off<<<nbN, BT, 0, stream>>>(pos, pos4, off_row, off_col, pad16);

  // CSR build
  if (padded){
    k_place_pad<<<nbE, BT, 0, stream>>>(ei, pos4, cnt_row, cnt_col,
                                        row_dst, row_w, col_src, col_rp, col_w);
    k_padzero<<<nbN16, BT, 0, stream>>>(cnt_row, cnt_col,
                                        row_dst, row_w, col_src, col_w);
  } else {
    k_count<<<nbE4, BT, 0, stream>>>(ei, cnt_row, cnt_col);
    k_blocksum<<<dim3(nbN,2), BT, 0, stream>>>(cnt_row, cnt_col, bsum);
    k_scan_bsum<<<dim3(1,2), 512, 0, stream>>>(bsum, nbN);
    k_offsets<<<dim3(nbN,2), BT, 0, stream>>>(cnt_row, cnt_col, bsum,
                                              off_row, off_col, cur_row, cur_col);
    k_place<<<nbE, BT, 0, stream>>>(ei, pos4, cur_row, cur_col,
                                    row_dst, row_w, col_src, col_rp, col_w);
  }

  // forward
  k_dinv_y1<<<nbN16, BT, 0, stream>>>(col_w, off_col, cnt_col, emb, z, W1, dinv, ys1);
  k_conv1_mid<<<nbN16, BT, 0, stream>>>(col_src, col_w, off_col, cnt_col, dinv, ys1,
                                        b1, Wl1, bl1, W2, ys2, masks, pad16);
  k_conv2_out<<<nbN16, BT, 0, stream>>>(col_src, col_w, off_col, cnt_col, dinv, ys2,
                                        batch, b2, Wl2, bl2, Wl3, bl3, Eout, ds3,
                                        gdiag, pad16);

  // backward
  k_bwd2mid<<<nbN16, BT, 0, stream>>>(row_dst, row_w, off_row, cnt_row, dinv, ys1, ys2,
                                      ds3, masks, W2, Wl1, gn_row, ds1, gdiag, pad16);
  k_bwd1row<<<nbN16, BT, 0, stream>>>(row_dst, row_w, off_row, cnt_row, ys1, ds1,
                                      gn_row, gdinv_row, pad16);
  k_gdeg<<<nbN16, BT, 0, stream>>>(col_rp, col_w, off_col, cnt_col, gn_row, gdinv_row,
                                   gdiag, dinv, pos4, gns_col, pn4);
  k_force<<<nbN16, BT, 0, stream>>>(row_dst, row_w, off_row, cnt_row,
                                    col_src, col_w, off_col, cnt_col,
                                    gn_row, gns_col, pn4, F);
}